// Round 13
// baseline (812.803 us; speedup 1.0000x reference)
//
#include <hip/hip_runtime.h>
#include <hip/hip_bf16.h>

#define N_A 100000
#define N_B 100000
#define E_AA 400000
#define E_AB 800000
#define E_BA 800000
#define E_ALL (E_AA + E_BA + E_AB)              // 2,000,000
#define SCAN_N (2*N_A + N_B)                    // 300000 concatenated degree slots
#define SCAN_BLOCKS ((SCAN_N + 1023) / 1024)    // 293

__device__ __forceinline__ void fma4(float4& a, float s, const float4 w) {
    a.x += s*w.x; a.y += s*w.y; a.z += s*w.z; a.w += s*w.w;
}

// ---------------------------------------------------------------------------
// Layer-0 closed form: sv = [cA, u_aa, v_ba, cB, w_ab]
// ---------------------------------------------------------------------------
__global__ void precompute_vecs(const float* __restrict__ emb_A, const float* __restrict__ emb_B,
    const float* __restrict__ W_aa, const float* __restrict__ b_aa,
    const float* __restrict__ W_ab, const float* __restrict__ b_ab,
    const float* __restrict__ W_ba, const float* __restrict__ b_ba,
    const float* __restrict__ Wn_A, const float* __restrict__ bn_A,
    const float* __restrict__ Wn_B, const float* __restrict__ bn_B,
    float* __restrict__ sv)
{
    __shared__ float ea[64], eb[64], maa[64], mab[64], mba[64];
    int j = threadIdx.x;
    ea[j] = emb_A[j];
    eb[j] = emb_B[j];
    __syncthreads();
    float s_aa = b_aa[j], s_ab = b_ab[j], s_ba = b_ba[j];
    for (int k = 0; k < 64; ++k) {
        s_aa += ea[k] * W_aa[k*64 + j];
        s_ab += ea[k] * W_ab[k*64 + j];
        s_ba += eb[k] * W_ba[k*64 + j];
    }
    maa[j] = fmaxf(s_aa, 0.f);
    mab[j] = fmaxf(s_ab, 0.f);
    mba[j] = fmaxf(s_ba, 0.f);
    __syncthreads();
    float cA = bn_A[j], u = 0.f, v = 0.f, cB = bn_B[j], w = 0.f;
    for (int k = 0; k < 64; ++k) {
        cA += ea[k]  * Wn_A[k*64 + j];
        u  += maa[k] * Wn_A[(64+k)*64 + j];
        v  += mba[k] * Wn_A[(128+k)*64 + j];
        cB += eb[k]  * Wn_B[k*64 + j];
        w  += mab[k] * Wn_B[(64+k)*64 + j];
    }
    sv[j] = cA; sv[64+j] = u; sv[128+j] = v; sv[192+j] = cB; sv[256+j] = w;
}

// merged degree histogram over all three edge types (concatenated sections)
__global__ void hist_all(const int* __restrict__ dst_aa, const int* __restrict__ dst_ba,
                         const int* __restrict__ dst_ab, int* __restrict__ deg)
{
    int i = blockIdx.x * 256 + threadIdx.x;
    if (i < E_AA)                 atomicAdd(deg + dst_aa[i], 1);
    else if (i < E_AA + E_BA)     atomicAdd(deg + N_A + dst_ba[i - E_AA], 1);
    else if (i < E_ALL)           atomicAdd(deg + 2*N_A + dst_ab[i - E_AA - E_BA], 1);
}

// merged counting-sort fill (positions are global across the concatenated scan)
__global__ void fill_all(const int* __restrict__ src_aa, const int* __restrict__ src_ba,
                         const int* __restrict__ src_ab,
                         const int* __restrict__ dst_aa, const int* __restrict__ dst_ba,
                         const int* __restrict__ dst_ab,
                         int* __restrict__ cur, int* __restrict__ perm)
{
    int i = blockIdx.x * 256 + threadIdx.x;
    int s, c;
    if (i < E_AA)                 { s = src_aa[i];              c = dst_aa[i]; }
    else if (i < E_AA + E_BA)     { s = src_ba[i - E_AA];       c = N_A + dst_ba[i - E_AA]; }
    else if (i < E_ALL)           { s = src_ab[i - E_AA - E_BA]; c = 2*N_A + dst_ab[i - E_AA - E_BA]; }
    else return;
    int p = atomicAdd(cur + c, 1);
    perm[p] = s;
}

// ---------------------------------------------------------------------------
// Hierarchical exclusive scan over the 300k concatenated degree array.
// ---------------------------------------------------------------------------
__global__ __launch_bounds__(1024) void scan_blocks(const int* __restrict__ deg,
                                                    int* __restrict__ scan_tmp,
                                                    int* __restrict__ partials)
{
    __shared__ int ps[1024];
    int tid = threadIdx.x;
    int gid = blockIdx.x * 1024 + tid;
    int v = (gid < SCAN_N) ? deg[gid] : 0;
    ps[tid] = v;
    __syncthreads();
    for (int off = 1; off < 1024; off <<= 1) {
        int t = (tid >= off) ? ps[tid - off] : 0;
        __syncthreads();
        ps[tid] += t;
        __syncthreads();
    }
    if (gid < SCAN_N) scan_tmp[gid] = ps[tid] - v;   // local exclusive
    if (tid == 1023) partials[blockIdx.x] = ps[1023];
}

__global__ __launch_bounds__(512) void scan_partials(int* __restrict__ partials)
{
    __shared__ int ps[512];
    int tid = threadIdx.x;
    int v = (tid < SCAN_BLOCKS) ? partials[tid] : 0;
    ps[tid] = v;
    __syncthreads();
    for (int off = 1; off < 512; off <<= 1) {
        int t = (tid >= off) ? ps[tid - off] : 0;
        __syncthreads();
        ps[tid] += t;
        __syncthreads();
    }
    partials[tid] = ps[tid] - v;                     // exclusive
    if (tid == 511) partials[512] = ps[511];         // grand total
}

__global__ __launch_bounds__(1024) void scan_finalize(const int* __restrict__ scan_tmp,
                                                      const int* __restrict__ partials,
                                                      int* __restrict__ rp,
                                                      int* __restrict__ cur)
{
    int gid = blockIdx.x * 1024 + threadIdx.x;
    if (gid < SCAN_N) {
        int v = scan_tmp[gid] + partials[blockIdx.x];
        rp[gid] = v;
        cur[gid] = v;
    }
    if (gid == 0) rp[SCAN_N] = partials[512];
}

__global__ void layer0_nodes(const int* __restrict__ deg_aa, const int* __restrict__ deg_ba,
                             const int* __restrict__ deg_ab, const float* __restrict__ sv,
                             float* __restrict__ hA1, float* __restrict__ hB1)
{
    __shared__ float s[320];
    for (int t = threadIdx.x; t < 320; t += blockDim.x)
        s[t] = sv[t];
    __syncthreads();
    int gid = blockIdx.x * blockDim.x + threadIdx.x;
    int total = (N_A + N_B) * 64;
    for (int idx = gid; idx < total; idx += gridDim.x * blockDim.x) {
        int i = idx >> 6, j = idx & 63;
        if (i < N_A) {
            float da = (float)deg_aa[i];
            float db = (float)deg_ba[i];
            hA1[idx] = fmaxf(s[j] + da * s[64+j] + db * s[128+j], 0.f);
        } else {
            int b = i - N_A;
            float dd = (float)deg_ab[b];
            hB1[(size_t)b*64 + j] = fmaxf(s[192+j] + dd * s[256+j], 0.f);
        }
    }
}

// ---------------------------------------------------------------------------
// GEMM body: out = relu(concat(srcs[0..NS-1]) @ Wn + bn), K = NS*64.
// W staged in LDS; 8 rows/thread so each ds_read_b128 of W feeds 8 rows ->
// LDS pipe (48 cy/wave/k4/src) < VALU (64 per-CU cy) -> VALU-bound.
// Block = 256 thr = 16 colgroups x 16 threadrows x 8 rows = 128 rows/block.
// Alias-safe: rows are thread-exclusive, read fully before written.
// ---------------------------------------------------------------------------
template<int NS>
__device__ __forceinline__ void gemm_body(int blk,
    const float* __restrict__ h, const float* r0, const float* r1,
    const float* __restrict__ Wn, const float* __restrict__ bn,
    float* out, int n)
{
    __shared__ float Ws[NS * 4096];
    int tid = threadIdx.x;
    for (int t = tid; t < NS * 4096; t += 256) Ws[t] = Wn[t];
    __syncthreads();
    int cg = tid & 15, tr = tid >> 4;
    int c0 = cg * 4;
    int row0 = blk * 128 + tr * 8;
    size_t off[8];
    #pragma unroll
    for (int i = 0; i < 8; ++i) {
        int rr = row0 + i; rr = (rr < n) ? rr : (n - 1);   // clamp tail reads
        off[i] = (size_t)rr * 64;
    }
    float4 bv = *(const float4*)&bn[c0];
    float4 acc[8];
    #pragma unroll
    for (int i = 0; i < 8; ++i) acc[i] = bv;
    const float* srcs[3] = {h, r0, r1};
    #pragma unroll
    for (int s = 0; s < NS; ++s) {
        const float* bp = srcs[s];
        #pragma unroll 4
        for (int k4 = 0; k4 < 16; ++k4) {
            const float* wb = &Ws[s*4096 + k4*256 + c0];
            float4 w0 = *(const float4*)(wb);
            float4 w1 = *(const float4*)(wb + 64);
            float4 w2 = *(const float4*)(wb + 128);
            float4 w3 = *(const float4*)(wb + 192);
            #pragma unroll
            for (int i = 0; i < 8; ++i) {
                float4 hv = *(const float4*)(bp + off[i] + k4 * 4);
                fma4(acc[i], hv.x, w0); fma4(acc[i], hv.y, w1);
                fma4(acc[i], hv.z, w2); fma4(acc[i], hv.w, w3);
            }
        }
    }
    #pragma unroll
    for (int i = 0; i < 8; ++i) {
        int rr = row0 + i;
        if (rr < n)
            *(float4*)(out + (size_t)rr * 64 + c0) =
                make_float4(fmaxf(acc[i].x,0.f), fmaxf(acc[i].y,0.f),
                            fmaxf(acc[i].z,0.f), fmaxf(acc[i].w,0.f));
    }
}

template<int NS>
__global__ __launch_bounds__(256) void node_update(
    const float* __restrict__ h,
    const float* r0,                  // no restrict: may alias out
    const float* r1,                  // no restrict: may alias out
    const float* __restrict__ Wn, const float* __restrict__ bn,
    float* out, int n)
{
    gemm_body<NS>(blockIdx.x, h, r0, r1, Wn, bn, out, n);
}

// Two independent NS=1 transforms in one dispatch (sectioned grid).
__global__ __launch_bounds__(256) void transform_dual(
    const float* __restrict__ hA, const float* __restrict__ WA,
    const float* __restrict__ bA, float* gA, int nA, int blocksA,
    const float* __restrict__ hB, const float* __restrict__ WB,
    const float* __restrict__ bB, float* gB, int nB)
{
    const float *h, *W, *b; float* g; int n, blk;
    if ((int)blockIdx.x < blocksA) { h = hA; W = WA; b = bA; g = gA; n = nA; blk = blockIdx.x; }
    else                           { h = hB; W = WB; b = bB; g = gB; n = nB; blk = blockIdx.x - blocksA; }
    gemm_body<1>(blk, h, nullptr, nullptr, W, b, g, n);
}

// ---------------------------------------------------------------------------
// CSR gathers: r[node] = sum over nbrs of g[src]. LDS-free, 16 lanes/node,
// float4/lane, 4-wide MLP unroll. Dual version handles aa+ba in one dispatch.
// ---------------------------------------------------------------------------
__device__ __forceinline__ float4 gather_row(
    const int* __restrict__ pm, const float* __restrict__ g,
    int e0, int e1, int l)
{
    float4 A = make_float4(0.f,0.f,0.f,0.f), B = make_float4(0.f,0.f,0.f,0.f);
    float4 C = make_float4(0.f,0.f,0.f,0.f), D = make_float4(0.f,0.f,0.f,0.f);
    int e = e0;
    for (; e + 3 < e1; e += 4) {
        int s0 = pm[e], s1 = pm[e+1], s2 = pm[e+2], s3 = pm[e+3];
        float4 v0 = *(const float4*)(g + (size_t)s0 * 64 + l * 4);
        float4 v1 = *(const float4*)(g + (size_t)s1 * 64 + l * 4);
        float4 v2 = *(const float4*)(g + (size_t)s2 * 64 + l * 4);
        float4 v3 = *(const float4*)(g + (size_t)s3 * 64 + l * 4);
        A.x += v0.x; A.y += v0.y; A.z += v0.z; A.w += v0.w;
        B.x += v1.x; B.y += v1.y; B.z += v1.z; B.w += v1.w;
        C.x += v2.x; C.y += v2.y; C.z += v2.z; C.w += v2.w;
        D.x += v3.x; D.y += v3.y; D.z += v3.z; D.w += v3.w;
    }
    for (; e < e1; ++e) {
        float4 v = *(const float4*)(g + (size_t)pm[e] * 64 + l * 4);
        A.x += v.x; A.y += v.y; A.z += v.z; A.w += v.w;
    }
    return make_float4(A.x+B.x+C.x+D.x, A.y+B.y+C.y+D.y,
                       A.z+B.z+C.z+D.z, A.w+B.w+C.w+D.w);
}

// aa (-> rA) and ba (-> rB) sections in one dispatch; rp is the concatenated
// rp_all so index nd works directly for both sections.
__global__ __launch_bounds__(256) void gather_dual(
    const int* __restrict__ rp, const int* __restrict__ pm,
    const float* __restrict__ gA, const float* __restrict__ gB,
    float* __restrict__ rA, float* __restrict__ rB)
{
    int gid = blockIdx.x * 256 + threadIdx.x;
    int nd = gid >> 4, l = gid & 15;
    if (nd >= 2 * N_A) return;
    int e0 = rp[nd], e1 = rp[nd + 1];
    const float* g = (nd < N_A) ? gA : gB;
    float4 res = gather_row(pm, g, e0, e1, l);
    float* r = (nd < N_A) ? (rA + (size_t)nd * 64) : (rB + (size_t)(nd - N_A) * 64);
    *(float4*)(r + l * 4) = res;
}

__global__ __launch_bounds__(256) void gather_csr(
    const int* __restrict__ rp, const int* __restrict__ pm,
    const float* __restrict__ g, float* __restrict__ r, int n)
{
    int gid = blockIdx.x * 256 + threadIdx.x;
    int node = gid >> 4, l = gid & 15;
    if (node >= n) return;
    float4 res = gather_row(pm, g, rp[node], rp[node + 1], l);
    *(float4*)(r + (size_t)node * 64 + l * 4) = res;
}

extern "C" void kernel_launch(void* const* d_in, const int* in_sizes, int n_in,
                              void* d_out, int out_size, void* d_ws, size_t ws_size,
                              hipStream_t stream)
{
    const int*   src_aa = (const int*)d_in[0];
    const int*   dst_aa = (const int*)d_in[1];
    const int*   src_ab = (const int*)d_in[2];
    const int*   dst_ab = (const int*)d_in[3];
    const int*   src_ba = (const int*)d_in[4];
    const int*   dst_ba = (const int*)d_in[5];
    const float* emb_A  = (const float*)d_in[6];
    const float* emb_B  = (const float*)d_in[7];
    const float* W_aa   = (const float*)d_in[8];
    const float* b_aa   = (const float*)d_in[9];
    const float* W_ab   = (const float*)d_in[10];
    const float* b_ab   = (const float*)d_in[11];
    const float* W_ba   = (const float*)d_in[12];
    const float* b_ba   = (const float*)d_in[13];
    const float* Wn_A   = (const float*)d_in[14];
    const float* bn_A   = (const float*)d_in[15];
    const float* Wn_B   = (const float*)d_in[16];
    const float* bn_B   = (const float*)d_in[17];

    // workspace (~116 MiB):
    // sv[512] | deg_all[300k] | scan_tmp[300k] | rp_all[300k+1] | cur_all[300k]
    // | partials[640] | perm_all[2M] | hA1 | hB1 | gX | gY
    // overlays: r_aa -> outA, r_ba -> outB, r_ab -> gY (after g_ba dead).
    float* ws   = (float*)d_ws;
    float* sv   = ws;
    int*   ib   = (int*)(ws + 512);
    int* deg_all  = ib;                 ib += SCAN_N;
    int* scan_tmp = ib;                 ib += SCAN_N;
    int* rp_all   = ib;                 ib += SCAN_N + 1;
    int* cur_all  = ib;                 ib += SCAN_N;
    int* partials = ib;                 ib += 640;
    int* perm_all = ib;                 ib += E_ALL;
    float* hA1 = (float*)ib;
    float* hB1 = hA1 + (size_t)N_A * 64;
    float* gX  = hB1 + (size_t)N_B * 64;   // g_aa, then reused as g_ab
    float* gY  = gX  + (size_t)N_A * 64;   // g_ba, then reused as r_ab

    float* outA = (float*)d_out;           // doubles as r_aa
    float* outB = outA + (size_t)N_A * 64; // doubles as r_ba (until update B)

    const int GB = 128;                    // rows per GEMM block
    int gridA  = (N_A + GB - 1) / GB;      // 782
    int gridB  = (N_B + GB - 1) / GB;      // 782

    hipMemsetAsync(deg_all, 0, (size_t)SCAN_N * sizeof(int), stream);

    precompute_vecs<<<1, 64, 0, stream>>>(emb_A, emb_B, W_aa, b_aa, W_ab, b_ab,
                                          W_ba, b_ba, Wn_A, bn_A, Wn_B, bn_B, sv);
    hist_all<<<(E_ALL + 255) / 256, 256, 0, stream>>>(dst_aa, dst_ba, dst_ab, deg_all);

    scan_blocks  <<<SCAN_BLOCKS, 1024, 0, stream>>>(deg_all, scan_tmp, partials);
    scan_partials<<<1, 512, 0, stream>>>(partials);
    scan_finalize<<<SCAN_BLOCKS, 1024, 0, stream>>>(scan_tmp, partials, rp_all, cur_all);

    layer0_nodes<<<4096, 256, 0, stream>>>(deg_all, deg_all + N_A, deg_all + 2*N_A,
                                           sv, hA1, hB1);

    fill_all<<<(E_ALL + 255) / 256, 256, 0, stream>>>(src_aa, src_ba, src_ab,
                                                      dst_aa, dst_ba, dst_ab,
                                                      cur_all, perm_all);

    // layer-1 edge transforms aa + ba in one dispatch
    transform_dual<<<gridA + gridB, 256, 0, stream>>>(
        hA1, W_aa + 4096, b_aa + 64, gX, N_A, gridA,
        hB1, W_ba + 4096, b_ba + 64, gY, N_B);

    // merged atomic-free CSR gathers: r_aa -> outA, r_ba -> outB
    gather_dual<<<(2 * N_A * 16) / 256, 256, 0, stream>>>(rp_all, perm_all,
                                                          gX, gY, outA, outB);

    // A update: concat [hA1, r_aa(outA), r_ba(outB)] -> outA
    node_update<3><<<gridA, 256, 0, stream>>>(hA1, outA, outB,
                                              Wn_A + 12288, bn_A + 64, outA, N_A);

    // gX dead -> g_ab; gY dead -> r_ab
    node_update<1><<<gridA, 256, 0, stream>>>(hA1, nullptr, nullptr,
                                              W_ab + 4096, b_ab + 64, gX, N_A);
    gather_csr<<<(N_B * 16) / 256, 256, 0, stream>>>(rp_all + 2*N_A, perm_all, gX, gY, N_B);

    // B update: concat [hB1, r_ab(gY)] -> outB
    node_update<2><<<gridB, 256, 0, stream>>>(hB1, gY, nullptr,
                                              Wn_B + 8192, bn_B + 64, outB, N_B);
}

// Round 14
// 600.742 us; speedup vs baseline: 1.3530x; 1.3530x over previous
//
#include <hip/hip_runtime.h>
#include <hip/hip_bf16.h>

#define N_A 100000
#define N_B 100000
#define E_AA 400000
#define E_AB 800000
#define E_BA 800000
#define E_ALL (E_AA + E_BA + E_AB)              // 2,000,000
#define SCAN_N (2*N_A + N_B)                    // 300000 concatenated degree slots
#define SCAN_BLOCKS ((SCAN_N + 1023) / 1024)    // 293
#define RGS 8                                   // range groups (hoped == 8 XCDs)
#define RSIZE ((SCAN_N + RGS - 1) / RGS)        // 37500

__device__ __forceinline__ void fma4(float4& a, float s, const float4 w) {
    a.x += s*w.x; a.y += s*w.y; a.z += s*w.z; a.w += s*w.w;
}

// ---------------------------------------------------------------------------
// Layer-0 closed form: sv = [cA, u_aa, v_ba, cB, w_ab]
// ---------------------------------------------------------------------------
__global__ void precompute_vecs(const float* __restrict__ emb_A, const float* __restrict__ emb_B,
    const float* __restrict__ W_aa, const float* __restrict__ b_aa,
    const float* __restrict__ W_ab, const float* __restrict__ b_ab,
    const float* __restrict__ W_ba, const float* __restrict__ b_ba,
    const float* __restrict__ Wn_A, const float* __restrict__ bn_A,
    const float* __restrict__ Wn_B, const float* __restrict__ bn_B,
    float* __restrict__ sv)
{
    __shared__ float ea[64], eb[64], maa[64], mab[64], mba[64];
    int j = threadIdx.x;
    ea[j] = emb_A[j];
    eb[j] = emb_B[j];
    __syncthreads();
    float s_aa = b_aa[j], s_ab = b_ab[j], s_ba = b_ba[j];
    for (int k = 0; k < 64; ++k) {
        s_aa += ea[k] * W_aa[k*64 + j];
        s_ab += ea[k] * W_ab[k*64 + j];
        s_ba += eb[k] * W_ba[k*64 + j];
    }
    maa[j] = fmaxf(s_aa, 0.f);
    mab[j] = fmaxf(s_ab, 0.f);
    mba[j] = fmaxf(s_ba, 0.f);
    __syncthreads();
    float cA = bn_A[j], u = 0.f, v = 0.f, cB = bn_B[j], w = 0.f;
    for (int k = 0; k < 64; ++k) {
        cA += ea[k]  * Wn_A[k*64 + j];
        u  += maa[k] * Wn_A[(64+k)*64 + j];
        v  += mba[k] * Wn_A[(128+k)*64 + j];
        cB += eb[k]  * Wn_B[k*64 + j];
        w  += mab[k] * Wn_B[(64+k)*64 + j];
    }
    sv[j] = cA; sv[64+j] = u; sv[128+j] = v; sv[192+j] = cB; sv[256+j] = w;
}

__device__ __forceinline__ int concat_dst(int i, const int* __restrict__ da,
                                          const int* __restrict__ db,
                                          const int* __restrict__ dc)
{
    if (i < E_AA)            return da[i];
    if (i < E_AA + E_BA)     return N_A + db[i - E_AA];
    return 2*N_A + dc[i - E_AA - E_BA];
}

// ---------------------------------------------------------------------------
// XCD-range-privatized histogram: block group (bid&7) commits only counters in
// its 37500-slice -> counter lines stay in one XCD's L2, no cross-XCD bounce.
// Correct regardless of actual block->XCD mapping (each edge commits once).
// ---------------------------------------------------------------------------
__global__ __launch_bounds__(256) void hist_x(
    const int* __restrict__ da, const int* __restrict__ db, const int* __restrict__ dc,
    int* __restrict__ deg)
{
    int range = blockIdx.x & (RGS - 1);
    int lo = range * RSIZE, hi = lo + RSIZE;
    int g = blockIdx.x >> 3;
    int stride = (gridDim.x >> 3) * 256;
    for (int i = g * 256 + threadIdx.x; i < E_ALL; i += stride) {
        int c = concat_dst(i, da, db, dc);
        if (c >= lo && c < hi) atomicAdd(deg + c, 1);
    }
}

// XCD-range-privatized counting-sort fill (same sweep structure).
__global__ __launch_bounds__(256) void fill_x(
    const int* __restrict__ sa, const int* __restrict__ sb, const int* __restrict__ sc,
    const int* __restrict__ da, const int* __restrict__ db, const int* __restrict__ dc,
    int* __restrict__ cur, int* __restrict__ perm)
{
    int range = blockIdx.x & (RGS - 1);
    int lo = range * RSIZE, hi = lo + RSIZE;
    int g = blockIdx.x >> 3;
    int stride = (gridDim.x >> 3) * 256;
    for (int i = g * 256 + threadIdx.x; i < E_ALL; i += stride) {
        int c = concat_dst(i, da, db, dc);
        if (c >= lo && c < hi) {
            int s;
            if (i < E_AA)            s = sa[i];
            else if (i < E_AA+E_BA)  s = sb[i - E_AA];
            else                     s = sc[i - E_AA - E_BA];
            int p = atomicAdd(cur + c, 1);
            perm[p] = s;
        }
    }
}

// ---------------------------------------------------------------------------
// Hierarchical exclusive scan over the 300k concatenated degree array.
// ---------------------------------------------------------------------------
__global__ __launch_bounds__(1024) void scan_blocks(const int* __restrict__ deg,
                                                    int* __restrict__ scan_tmp,
                                                    int* __restrict__ partials)
{
    __shared__ int ps[1024];
    int tid = threadIdx.x;
    int gid = blockIdx.x * 1024 + tid;
    int v = (gid < SCAN_N) ? deg[gid] : 0;
    ps[tid] = v;
    __syncthreads();
    for (int off = 1; off < 1024; off <<= 1) {
        int t = (tid >= off) ? ps[tid - off] : 0;
        __syncthreads();
        ps[tid] += t;
        __syncthreads();
    }
    if (gid < SCAN_N) scan_tmp[gid] = ps[tid] - v;   // local exclusive
    if (tid == 1023) partials[blockIdx.x] = ps[1023];
}

__global__ __launch_bounds__(512) void scan_partials(int* __restrict__ partials)
{
    __shared__ int ps[512];
    int tid = threadIdx.x;
    int v = (tid < SCAN_BLOCKS) ? partials[tid] : 0;
    ps[tid] = v;
    __syncthreads();
    for (int off = 1; off < 512; off <<= 1) {
        int t = (tid >= off) ? ps[tid - off] : 0;
        __syncthreads();
        ps[tid] += t;
        __syncthreads();
    }
    partials[tid] = ps[tid] - v;                     // exclusive
    if (tid == 511) partials[512] = ps[511];         // grand total
}

__global__ __launch_bounds__(1024) void scan_finalize(const int* __restrict__ scan_tmp,
                                                      const int* __restrict__ partials,
                                                      int* __restrict__ rp,
                                                      int* __restrict__ cur)
{
    int gid = blockIdx.x * 1024 + threadIdx.x;
    if (gid < SCAN_N) {
        int v = scan_tmp[gid] + partials[blockIdx.x];
        rp[gid] = v;
        cur[gid] = v;
    }
    if (gid == 0) rp[SCAN_N] = partials[512];
}

__global__ void layer0_nodes(const int* __restrict__ deg_aa, const int* __restrict__ deg_ba,
                             const int* __restrict__ deg_ab, const float* __restrict__ sv,
                             float* __restrict__ hA1, float* __restrict__ hB1)
{
    __shared__ float s[320];
    for (int t = threadIdx.x; t < 320; t += blockDim.x)
        s[t] = sv[t];
    __syncthreads();
    int gid = blockIdx.x * blockDim.x + threadIdx.x;
    int total = (N_A + N_B) * 64;
    for (int idx = gid; idx < total; idx += gridDim.x * blockDim.x) {
        int i = idx >> 6, j = idx & 63;
        if (i < N_A) {
            float da = (float)deg_aa[i];
            float db = (float)deg_ba[i];
            hA1[idx] = fmaxf(s[j] + da * s[64+j] + db * s[128+j], 0.f);
        } else {
            int b = i - N_A;
            float dd = (float)deg_ab[b];
            hB1[(size_t)b*64 + j] = fmaxf(s[192+j] + dd * s[256+j], 0.f);
        }
    }
}

// ---------------------------------------------------------------------------
// GEMM body: out = relu(concat(srcs[0..NS-1]) @ Wn + bn), K = NS*64.
// W staged in LDS; 4 rows/thread (named pointers, acc[4] -> ~90 VGPR, no
// spill) halves wave count vs 2-row. Block = 256 thr = 64 rows.
// Alias-safe: rows thread-exclusive, read fully before written.
// ---------------------------------------------------------------------------
template<int NS>
__device__ __forceinline__ void gemm_body(int blk,
    const float* __restrict__ h, const float* r0, const float* r1,
    const float* __restrict__ Wn, const float* __restrict__ bn,
    float* out, int n)
{
    __shared__ float Ws[NS * 4096];
    int tid = threadIdx.x;
    for (int t = tid; t < NS * 4096; t += 256) Ws[t] = Wn[t];
    __syncthreads();
    int cg = tid & 15, tr = tid >> 4;
    int c0 = cg * 4;
    int row0 = blk * 64 + tr * 4;
    int ra = row0,     rb = row0 + 1, rc = row0 + 2, rd = row0 + 3;
    ra = (ra < n) ? ra : n - 1;  rb = (rb < n) ? rb : n - 1;   // clamp tail reads
    rc = (rc < n) ? rc : n - 1;  rd = (rd < n) ? rd : n - 1;
    float4 bv = *(const float4*)&bn[c0];
    float4 acc0 = bv, acc1 = bv, acc2 = bv, acc3 = bv;
    const float* srcs[3] = {h, r0, r1};
    #pragma unroll
    for (int s = 0; s < NS; ++s) {
        const float* pa = srcs[s] + (size_t)ra * 64;
        const float* pb = srcs[s] + (size_t)rb * 64;
        const float* pc = srcs[s] + (size_t)rc * 64;
        const float* pd = srcs[s] + (size_t)rd * 64;
        #pragma unroll 4
        for (int k4 = 0; k4 < 16; ++k4) {
            const float* wb = &Ws[s*4096 + k4*256 + c0];
            float4 w0 = *(const float4*)(wb);
            float4 w1 = *(const float4*)(wb + 64);
            float4 w2 = *(const float4*)(wb + 128);
            float4 w3 = *(const float4*)(wb + 192);
            float4 ha = *(const float4*)(pa + k4 * 4);
            float4 hb = *(const float4*)(pb + k4 * 4);
            float4 hc = *(const float4*)(pc + k4 * 4);
            float4 hd = *(const float4*)(pd + k4 * 4);
            fma4(acc0, ha.x, w0); fma4(acc0, ha.y, w1); fma4(acc0, ha.z, w2); fma4(acc0, ha.w, w3);
            fma4(acc1, hb.x, w0); fma4(acc1, hb.y, w1); fma4(acc1, hb.z, w2); fma4(acc1, hb.w, w3);
            fma4(acc2, hc.x, w0); fma4(acc2, hc.y, w1); fma4(acc2, hc.z, w2); fma4(acc2, hc.w, w3);
            fma4(acc3, hd.x, w0); fma4(acc3, hd.y, w1); fma4(acc3, hd.z, w2); fma4(acc3, hd.w, w3);
        }
    }
    if (row0 + 0 < n) *(float4*)(out + (size_t)(row0+0)*64 + c0) =
        make_float4(fmaxf(acc0.x,0.f), fmaxf(acc0.y,0.f), fmaxf(acc0.z,0.f), fmaxf(acc0.w,0.f));
    if (row0 + 1 < n) *(float4*)(out + (size_t)(row0+1)*64 + c0) =
        make_float4(fmaxf(acc1.x,0.f), fmaxf(acc1.y,0.f), fmaxf(acc1.z,0.f), fmaxf(acc1.w,0.f));
    if (row0 + 2 < n) *(float4*)(out + (size_t)(row0+2)*64 + c0) =
        make_float4(fmaxf(acc2.x,0.f), fmaxf(acc2.y,0.f), fmaxf(acc2.z,0.f), fmaxf(acc2.w,0.f));
    if (row0 + 3 < n) *(float4*)(out + (size_t)(row0+3)*64 + c0) =
        make_float4(fmaxf(acc3.x,0.f), fmaxf(acc3.y,0.f), fmaxf(acc3.z,0.f), fmaxf(acc3.w,0.f));
}

template<int NS>
__global__ __launch_bounds__(256) void node_update(
    const float* __restrict__ h,
    const float* r0,                  // no restrict: may alias out
    const float* r1,                  // no restrict: may alias out
    const float* __restrict__ Wn, const float* __restrict__ bn,
    float* out, int n)
{
    gemm_body<NS>(blockIdx.x, h, r0, r1, Wn, bn, out, n);
}

// Two independent NS=1 transforms in one dispatch (sectioned grid).
__global__ __launch_bounds__(256) void transform_dual(
    const float* __restrict__ hA, const float* __restrict__ WA,
    const float* __restrict__ bA, float* gA, int nA, int blocksA,
    const float* __restrict__ hB, const float* __restrict__ WB,
    const float* __restrict__ bB, float* gB, int nB)
{
    const float *h, *W, *b; float* g; int n, blk;
    if ((int)blockIdx.x < blocksA) { h = hA; W = WA; b = bA; g = gA; n = nA; blk = blockIdx.x; }
    else                           { h = hB; W = WB; b = bB; g = gB; n = nB; blk = blockIdx.x - blocksA; }
    gemm_body<1>(blk, h, nullptr, nullptr, W, b, g, n);
}

// ---------------------------------------------------------------------------
// CSR gathers: r[node] = sum over nbrs of g[src]. LDS-free, 16 lanes/node,
// float4/lane, 4-wide MLP unroll. Dual version handles aa+ba in one dispatch.
// ---------------------------------------------------------------------------
__device__ __forceinline__ float4 gather_row(
    const int* __restrict__ pm, const float* __restrict__ g,
    int e0, int e1, int l)
{
    float4 A = make_float4(0.f,0.f,0.f,0.f), B = make_float4(0.f,0.f,0.f,0.f);
    float4 C = make_float4(0.f,0.f,0.f,0.f), D = make_float4(0.f,0.f,0.f,0.f);
    int e = e0;
    for (; e + 3 < e1; e += 4) {
        int s0 = pm[e], s1 = pm[e+1], s2 = pm[e+2], s3 = pm[e+3];
        float4 v0 = *(const float4*)(g + (size_t)s0 * 64 + l * 4);
        float4 v1 = *(const float4*)(g + (size_t)s1 * 64 + l * 4);
        float4 v2 = *(const float4*)(g + (size_t)s2 * 64 + l * 4);
        float4 v3 = *(const float4*)(g + (size_t)s3 * 64 + l * 4);
        A.x += v0.x; A.y += v0.y; A.z += v0.z; A.w += v0.w;
        B.x += v1.x; B.y += v1.y; B.z += v1.z; B.w += v1.w;
        C.x += v2.x; C.y += v2.y; C.z += v2.z; C.w += v2.w;
        D.x += v3.x; D.y += v3.y; D.z += v3.z; D.w += v3.w;
    }
    for (; e < e1; ++e) {
        float4 v = *(const float4*)(g + (size_t)pm[e] * 64 + l * 4);
        A.x += v.x; A.y += v.y; A.z += v.z; A.w += v.w;
    }
    return make_float4(A.x+B.x+C.x+D.x, A.y+B.y+C.y+D.y,
                       A.z+B.z+C.z+D.z, A.w+B.w+C.w+D.w);
}

__global__ __launch_bounds__(256) void gather_dual(
    const int* __restrict__ rp, const int* __restrict__ pm,
    const float* __restrict__ gA, const float* __restrict__ gB,
    float* __restrict__ rA, float* __restrict__ rB)
{
    int gid = blockIdx.x * 256 + threadIdx.x;
    int nd = gid >> 4, l = gid & 15;
    if (nd >= 2 * N_A) return;
    int e0 = rp[nd], e1 = rp[nd + 1];
    const float* g = (nd < N_A) ? gA : gB;
    float4 res = gather_row(pm, g, e0, e1, l);
    float* r = (nd < N_A) ? (rA + (size_t)nd * 64) : (rB + (size_t)(nd - N_A) * 64);
    *(float4*)(r + l * 4) = res;
}

__global__ __launch_bounds__(256) void gather_csr(
    const int* __restrict__ rp, const int* __restrict__ pm,
    const float* __restrict__ g, float* __restrict__ r, int n)
{
    int gid = blockIdx.x * 256 + threadIdx.x;
    int node = gid >> 4, l = gid & 15;
    if (node >= n) return;
    float4 res = gather_row(pm, g, rp[node], rp[node + 1], l);
    *(float4*)(r + (size_t)node * 64 + l * 4) = res;
}

extern "C" void kernel_launch(void* const* d_in, const int* in_sizes, int n_in,
                              void* d_out, int out_size, void* d_ws, size_t ws_size,
                              hipStream_t stream)
{
    const int*   src_aa = (const int*)d_in[0];
    const int*   dst_aa = (const int*)d_in[1];
    const int*   src_ab = (const int*)d_in[2];
    const int*   dst_ab = (const int*)d_in[3];
    const int*   src_ba = (const int*)d_in[4];
    const int*   dst_ba = (const int*)d_in[5];
    const float* emb_A  = (const float*)d_in[6];
    const float* emb_B  = (const float*)d_in[7];
    const float* W_aa   = (const float*)d_in[8];
    const float* b_aa   = (const float*)d_in[9];
    const float* W_ab   = (const float*)d_in[10];
    const float* b_ab   = (const float*)d_in[11];
    const float* W_ba   = (const float*)d_in[12];
    const float* b_ba   = (const float*)d_in[13];
    const float* Wn_A   = (const float*)d_in[14];
    const float* bn_A   = (const float*)d_in[15];
    const float* Wn_B   = (const float*)d_in[16];
    const float* bn_B   = (const float*)d_in[17];

    // workspace (~116 MiB):
    // sv[512] | deg_all[300k] | scan_tmp[300k] | rp_all[300k+1] | cur_all[300k]
    // | partials[640] | perm_all[2M] | hA1 | hB1 | gX | gY
    // overlays: r_aa -> outA, r_ba -> outB, r_ab -> gY (after g_ba dead).
    float* ws   = (float*)d_ws;
    float* sv   = ws;
    int*   ib   = (int*)(ws + 512);
    int* deg_all  = ib;                 ib += SCAN_N;
    int* scan_tmp = ib;                 ib += SCAN_N;
    int* rp_all   = ib;                 ib += SCAN_N + 1;
    int* cur_all  = ib;                 ib += SCAN_N;
    int* partials = ib;                 ib += 640;
    int* perm_all = ib;                 ib += E_ALL;
    float* hA1 = (float*)ib;
    float* hB1 = hA1 + (size_t)N_A * 64;
    float* gX  = hB1 + (size_t)N_B * 64;   // g_aa, then reused as g_ab
    float* gY  = gX  + (size_t)N_A * 64;   // g_ba, then reused as r_ab

    float* outA = (float*)d_out;           // doubles as r_aa
    float* outB = outA + (size_t)N_A * 64; // doubles as r_ba (until update B)

    const int GB = 64;                     // rows per GEMM block (4 rows/thread)
    int gridA  = (N_A + GB - 1) / GB;      // 1563
    int gridB  = (N_B + GB - 1) / GB;      // 1563

    hipMemsetAsync(deg_all, 0, (size_t)SCAN_N * sizeof(int), stream);

    precompute_vecs<<<1, 64, 0, stream>>>(emb_A, emb_B, W_aa, b_aa, W_ab, b_ab,
                                          W_ba, b_ba, Wn_A, bn_A, Wn_B, bn_B, sv);
    hist_x<<<2048, 256, 0, stream>>>(dst_aa, dst_ba, dst_ab, deg_all);

    scan_blocks  <<<SCAN_BLOCKS, 1024, 0, stream>>>(deg_all, scan_tmp, partials);
    scan_partials<<<1, 512, 0, stream>>>(partials);
    scan_finalize<<<SCAN_BLOCKS, 1024, 0, stream>>>(scan_tmp, partials, rp_all, cur_all);

    layer0_nodes<<<4096, 256, 0, stream>>>(deg_all, deg_all + N_A, deg_all + 2*N_A,
                                           sv, hA1, hB1);

    fill_x<<<2048, 256, 0, stream>>>(src_aa, src_ba, src_ab,
                                     dst_aa, dst_ba, dst_ab,
                                     cur_all, perm_all);

    // layer-1 edge transforms aa + ba in one dispatch
    transform_dual<<<gridA + gridB, 256, 0, stream>>>(
        hA1, W_aa + 4096, b_aa + 64, gX, N_A, gridA,
        hB1, W_ba + 4096, b_ba + 64, gY, N_B);

    // merged atomic-free CSR gathers: r_aa -> outA, r_ba -> outB
    gather_dual<<<(2 * N_A * 16) / 256, 256, 0, stream>>>(rp_all, perm_all,
                                                          gX, gY, outA, outB);

    // A update: concat [hA1, r_aa(outA), r_ba(outB)] -> outA
    node_update<3><<<gridA, 256, 0, stream>>>(hA1, outA, outB,
                                              Wn_A + 12288, bn_A + 64, outA, N_A);

    // gX dead -> g_ab; gY dead -> r_ab
    node_update<1><<<gridA, 256, 0, stream>>>(hA1, nullptr, nullptr,
                                              W_ab + 4096, b_ab + 64, gX, N_A);
    gather_csr<<<(N_B * 16) / 256, 256, 0, stream>>>(rp_all + 2*N_A, perm_all, gX, gY, N_B);

    // B update: concat [hB1, r_ab(gY)] -> outB
    node_update<2><<<gridB, 256, 0, stream>>>(hB1, gY, nullptr,
                                              Wn_B + 8192, bn_B + 64, outB, N_B);
}